// Round 8
// baseline (252.269 us; speedup 1.0000x reference)
//
#include <hip/hip_runtime.h>
#include <hip/hip_cooperative_groups.h>
#include <math.h>

namespace cg = cooperative_groups;

#define NN 8192
#define DD 512
#define CC 1000
#define CP 1024   // padded C
#define CPD (CP*DD)

typedef __attribute__((ext_vector_type(8))) short short8;     // bf16x8 MFMA frag
typedef __attribute__((ext_vector_type(4))) float f32x4;
typedef __attribute__((ext_vector_type(4))) unsigned short us4;
typedef __attribute__((ext_vector_type(8))) unsigned short us8;
typedef __attribute__((ext_vector_type(4))) unsigned int ui4;

__device__ __forceinline__ float bf2f(unsigned short u){
  union{unsigned int i; float f;} v; v.i = ((unsigned int)u)<<16; return v.f;
}
__device__ __forceinline__ unsigned short f2bf(float f){
  union{float f; unsigned int i;} v; v.f = f;
  unsigned int r = v.i + 0x7FFF + ((v.i>>16)&1);   // RNE
  return (unsigned short)(r>>16);
}
__device__ __forceinline__ float waveRedSum(float v){
  #pragma unroll
  for(int o=32;o;o>>=1) v += __shfl_xor(v,o,64);
  return v;
}
__device__ __forceinline__ float waveRedMax(float v){
  #pragma unroll
  for(int o=32;o;o>>=1) v = fmaxf(v,__shfl_xor(v,o,64));
  return v;
}
__device__ __forceinline__ void gload_lds16(const void* g, void* l){
  __builtin_amdgcn_global_load_lds((const __attribute__((address_space(1))) void*)g,
                                   (__attribute__((address_space(3))) void*)l, 16, 0, 0);
}

// ---- K1: merged prep. Blocks interleaved 2 castF : 1 softmaxT (512 groups of 3).
__global__ __launch_bounds__(256) void k_prep(const float* __restrict__ F,
                                              const float* __restrict__ L,
                                              unsigned short* __restrict__ FbT,
                                              unsigned short* __restrict__ Fb,
                                              float* __restrict__ gpart,
                                              unsigned short* __restrict__ PbT){
  __shared__ __align__(16) char smem[8*1028*4];   // 32.9 KB union
  int bid = blockIdx.x;
  int grp = bid/3, r = bid - grp*3;
  int t = threadIdx.x;

  if(r < 2){
    // ---------- castF path, block index cb in [0,1024) ----------
    int cb = grp*2 + r;
    unsigned short* lds = (unsigned short*)smem;           // [64*68]
    float* gq = (float*)(smem + 64*68*2);                  // [16*64]
    int i0 = (cb & 127)*64, d0 = (cb >> 7)*64;
    int cx = t&15, ry = t>>4;
    float ca0=0.f,ca1=0.f,ca2=0.f,ca3=0.f;
    #pragma unroll
    for(int rr=0;rr<4;rr++){
      int row = rr*16 + ry;
      f32x4 fv = *(const f32x4*)&F[(size_t)(i0+row)*DD + d0 + cx*4];
      us4 u; u[0]=f2bf(fv[0]); u[1]=f2bf(fv[1]); u[2]=f2bf(fv[2]); u[3]=f2bf(fv[3]);
      *(us4*)&lds[row*68 + cx*4] = u;
      *(us4*)&Fb[(size_t)(i0+row)*DD + d0 + cx*4] = u;
      ca0+=fv[0]; ca1+=fv[1]; ca2+=fv[2]; ca3+=fv[3];
    }
    {
      f32x4 cv; cv[0]=ca0; cv[1]=ca1; cv[2]=ca2; cv[3]=ca3;
      *(f32x4*)&gq[ry*64 + cx*4] = cv;
    }
    __syncthreads();
    #pragma unroll
    for(int rr=0;rr<4;rr++){
      int d = rr*16 + ry;
      us4 u;
      #pragma unroll
      for(int q=0;q<4;q++) u[q] = lds[(cx*4+q)*68 + d];
      *(us4*)&FbT[(size_t)(d0+d)*NN + i0 + cx*4] = u;
    }
    __syncthreads();
    if(t<64){
      float s=0.f;
      #pragma unroll
      for(int j=0;j<16;j++) s += gq[j*64+t];
      gpart[(cb&127)*DD + d0 + t] = s;
    }
  } else {
    // ---------- softmaxT path, block index sb in [0,512) ----------
    int sb = grp;
    unsigned int (*lt)[1028] = (unsigned int(*)[1028])smem;
    int l = t&63, w = t>>6;
    int i0 = sb*16;
    #pragma unroll
    for(int q=0;q<4;q++){
      int rr = w*4 + q;
      int row = i0 + rr;
      const float* lr = L + (size_t)row*CC;
      float v[16]; float mx = -1e30f;
      #pragma unroll
      for(int k=0;k<16;k++){ int c = l + 64*k; v[k] = (c<CC)? lr[c] : -1e30f; mx = fmaxf(mx,v[k]); }
      mx = waveRedMax(mx);
      float s = 0.f;
      #pragma unroll
      for(int k=0;k<16;k++){ v[k] = __expf(v[k]-mx); s += v[k]; }
      s = waveRedSum(s);
      float inv = 1.0f/s;
      #pragma unroll
      for(int k=0;k<16;k++){
        int c = l + 64*k;
        float p = v[k]*inv + 1e-8f;
        unsigned short h = (c<CC)? f2bf(p) : (unsigned short)0;
        *((unsigned short*)&lt[rr>>1][c] + (rr&1)) = h;
      }
    }
    __syncthreads();
    #pragma unroll
    for(int k=0;k<4;k++){
      int c = t + 256*k;
      ui4 a, b;
      #pragma unroll
      for(int j=0;j<4;j++){ a[j] = lt[j][c]; b[j] = lt[j+4][c]; }
      *(ui4*)&PbT[(size_t)c*NN + i0]     = a;
      *(ui4*)&PbT[(size_t)c*NN + i0 + 8] = b;
    }
  }
}

// ---- K2: cooperative mega-kernel: gemm1+gred | redT+invr | gemm2+KL | finalize
__global__ __launch_bounds__(256,2) void k_main(const unsigned short* __restrict__ PbT,  // [1024][8192]
                                                const unsigned short* __restrict__ FbT,  // [512][8192]
                                                unsigned short* __restrict__ Tpb,
                                                const float* __restrict__ gpart,
                                                float* __restrict__ g,
                                                const unsigned short* __restrict__ Fb,   // [8192][512]
                                                unsigned short* __restrict__ Ttb,        // [1024][512]
                                                float* __restrict__ invr,
                                                float* __restrict__ partials,
                                                float* __restrict__ out){
  cg::grid_group grid = cg::this_grid();
  __shared__ __align__(16) unsigned short Al[128*64];
  __shared__ __align__(16) unsigned short Bl[128*64];
  __shared__ float rs[4][64];
  __shared__ float red[4];
  int bid = blockIdx.x;
  int t = threadIdx.x, l = t&63, w = t>>6;
  int wm = w>>1, wn = w&1;
  int srow = w*32 + (l>>3);
  int scl  = (l&7) ^ (srow&7);                 // pre-swizzled source chunk
  unsigned short* AlB = Al + (w*32)*64;
  unsigned short* BlB = Bl + (w*32)*64;
  int Lsw = (bid&7)*64 + (bid>>3);             // XCD-chunked bijective swizzle (512%8==0)

  // ================= phase 1: GEMM1 (Tpb[z] = PbT x FbT^T chunk) + gred =================
  {
    int bx = Lsw&7, by = (Lsw>>3)&3, bz = Lsw>>5;
    int m0 = bx*128, n0 = by*128, k0 = bz*512;
    f32x4 acc[4][4] = {};
    const unsigned short* Ab = PbT + (size_t)(m0 + srow)*NN + k0 + scl*8;
    const unsigned short* Bb = FbT + (size_t)(n0 + srow)*NN + k0 + scl*8;
    for(int kt=0; kt<512; kt+=64){
      __syncthreads();
      #pragma unroll
      for(int q=0;q<4;q++){
        gload_lds16(Ab + (size_t)q*8*NN + kt, AlB + q*8*64);
        gload_lds16(Bb + (size_t)q*8*NN + kt, BlB + q*8*64);
      }
      asm volatile("s_waitcnt vmcnt(0)" ::: "memory");
      __syncthreads();
      #pragma unroll
      for(int ks=0;ks<2;ks++){
        short8 af[4], bf[4];
        #pragma unroll
        for(int mi=0;mi<4;mi++){
          int rr = wm*64 + mi*16 + (l&15);
          int ch = ((ks<<2) + (l>>4)) ^ (rr&7);
          af[mi] = *(const short8*)&Al[rr*64 + ch*8];
        }
        #pragma unroll
        for(int ni=0;ni<4;ni++){
          int rr = wn*64 + ni*16 + (l&15);
          int ch = ((ks<<2) + (l>>4)) ^ (rr&7);
          bf[ni] = *(const short8*)&Bl[rr*64 + ch*8];
        }
        #pragma unroll
        for(int mi=0;mi<4;mi++)
          #pragma unroll
          for(int ni=0;ni<4;ni++)
            acc[mi][ni] = __builtin_amdgcn_mfma_f32_16x16x32_bf16(af[mi], bf[ni], acc[mi][ni], 0,0,0);
      }
    }
    unsigned short* Tz = Tpb + (size_t)bz*CPD;
    int rbase = (l>>4)*4;
    #pragma unroll
    for(int mi=0;mi<4;mi++){
      int c = m0 + wm*64 + mi*16 + rbase;
      #pragma unroll
      for(int ni=0;ni<4;ni++){
        int d = n0 + wn*64 + ni*16 + (l&15);
        #pragma unroll
        for(int j=0;j<4;j++)
          Tz[(size_t)(c+j)*DD + d] = f2bf(acc[mi][ni][j]);
      }
    }
    if(bid < 8){   // gred: g[d] = sum over 128 gpart groups
      int d = bid*64 + (t&63);
      int q = t>>6;
      float s = 0.f;
      #pragma unroll
      for(int j=0;j<32;j++) s += gpart[(size_t)(q*32+j)*DD + d];
      rs[q][t&63] = s;
      __syncthreads();
      if(q==0) g[d] = rs[0][t&63]+rs[1][t&63]+rs[2][t&63]+rs[3][t&63];
    }
  }
  grid.sync();

  // ================= phase 2: redT (Ttb = bf16 sum_z Tpb[z]) + invr =================
  {
    size_t i = ((size_t)bid*256 + (size_t)t)*4;     // 512*256*4 = CPD
    f32x4 s0 = {0.f,0.f,0.f,0.f};
    #pragma unroll
    for(int z=0;z<16;z++){
      us4 v = *(const us4*)&Tpb[(size_t)z*CPD + i];
      s0[0]+=bf2f(v[0]); s0[1]+=bf2f(v[1]); s0[2]+=bf2f(v[2]); s0[3]+=bf2f(v[3]);
    }
    us4 u; u[0]=f2bf(s0[0]); u[1]=f2bf(s0[1]); u[2]=f2bf(s0[2]); u[3]=f2bf(s0[3]);
    *(us4*)&Ttb[i] = u;
    // invr: 16 rows/block, 16 lanes/row x 32 d each
    int row = bid*16 + (t>>4);
    int seg = (t&15)*32;
    const unsigned short* fr = Fb + (size_t)row*DD + seg;
    const float* gr = g + seg;
    float s = 0.f;
    #pragma unroll
    for(int j=0;j<4;j++){
      us8 f8 = *(const us8*)&fr[j*8];
      f32x4 ga = *(const f32x4*)&gr[j*8];
      f32x4 gb = *(const f32x4*)&gr[j*8+4];
      s += bf2f(f8[0])*ga[0]+bf2f(f8[1])*ga[1]+bf2f(f8[2])*ga[2]+bf2f(f8[3])*ga[3]
         + bf2f(f8[4])*gb[0]+bf2f(f8[5])*gb[1]+bf2f(f8[6])*gb[2]+bf2f(f8[7])*gb[3];
    }
    s += __shfl_xor(s,1,64); s += __shfl_xor(s,2,64);
    s += __shfl_xor(s,4,64); s += __shfl_xor(s,8,64);
    if((t&15)==0) invr[row] = 1.0f/(s - 1.0f);
  }
  grid.sync();

  // ================= phase 3: GEMM2 (M = Fb x Ttb^T) + KL epilogue =================
  {
    int n0 = (Lsw&7)*128;          // c-tile
    int m0 = (Lsw>>3)*128;         // i-tile
    f32x4 acc[4][4] = {};
    const unsigned short* Ab = Fb + (size_t)(m0 + srow)*DD + scl*8;
    const unsigned short* Bb = Ttb + (size_t)(n0 + srow)*DD + scl*8;
    for(int kt=0; kt<512; kt+=64){
      __syncthreads();
      #pragma unroll
      for(int q=0;q<4;q++){
        gload_lds16(Ab + (size_t)q*8*DD + kt, AlB + q*8*64);
        gload_lds16(Bb + (size_t)q*8*DD + kt, BlB + q*8*64);
      }
      asm volatile("s_waitcnt vmcnt(0)" ::: "memory");
      __syncthreads();
      #pragma unroll
      for(int ks=0;ks<2;ks++){
        short8 af[4], bf[4];
        #pragma unroll
        for(int mi=0;mi<4;mi++){
          int rr = wm*64 + mi*16 + (l&15);
          int ch = ((ks<<2) + (l>>4)) ^ (rr&7);
          af[mi] = *(const short8*)&Al[rr*64 + ch*8];
        }
        #pragma unroll
        for(int ni=0;ni<4;ni++){
          int rr = wn*64 + ni*16 + (l&15);
          int ch = ((ks<<2) + (l>>4)) ^ (rr&7);
          bf[ni] = *(const short8*)&Bl[rr*64 + ch*8];
        }
        #pragma unroll
        for(int mi=0;mi<4;mi++)
          #pragma unroll
          for(int ni=0;ni<4;ni++)
            acc[mi][ni] = __builtin_amdgcn_mfma_f32_16x16x32_bf16(af[mi], bf[ni], acc[mi][ni], 0,0,0);
      }
    }
    float kl = 0.f;
    int rbase = (l>>4)*4;
    #pragma unroll
    for(int mi=0;mi<4;mi++){
      int i_base = m0 + wm*64 + mi*16 + rbase;
      f32x4 ir4 = *(const f32x4*)&invr[i_base];
      #pragma unroll
      for(int ni=0;ni<4;ni++){
        int c = n0 + wn*64 + ni*16 + (l&15);
        if(c < CC){
          us4 p4 = *(const us4*)&PbT[(size_t)c*NN + i_base];
          #pragma unroll
          for(int j=0;j<4;j++){
            float p = bf2f(p4[j]);
            float ws = (acc[mi][ni][j] - p) * ir4[j];
            kl += ws * (__logf(ws) - __logf(p));
          }
        }
      }
    }
    kl = waveRedSum(kl);
    if(l==0) red[w]=kl;
    __syncthreads();
    if(t==0) partials[Lsw] = red[0]+red[1]+red[2]+red[3];
  }
  grid.sync();

  // ================= phase 4: finalize (block 0, double) =================
  if(bid==0){
    double* ds = (double*)Al;
    double s = (double)partials[t] + (double)partials[t+256];
    ds[t] = s;
    __syncthreads();
    #pragma unroll
    for(int o=128;o;o>>=1){
      if(t<o) ds[t] += ds[t+o];
      __syncthreads();
    }
    if(t==0) out[0] = (float)(ds[0] / (double)NN);
  }
}

extern "C" void kernel_launch(void* const* d_in, const int* in_sizes, int n_in,
                              void* d_out, int out_size, void* d_ws, size_t ws_size,
                              hipStream_t stream){
  const float* F = (const float*)d_in[0];   // [8192][512]
  const float* L = (const float*)d_in[1];   // [8192][1000]
  float* out = (float*)d_out;

  unsigned char* w8 = (unsigned char*)d_ws;
  unsigned short* FbT = (unsigned short*)w8;                   // 512*8192*2      = 8 MB
  unsigned short* PbT = (unsigned short*)(w8 + (8u<<20));      // 1024*8192*2     = 16 MB
  unsigned short* Tpb = (unsigned short*)(w8 + (24u<<20));     // 16*1024*512*2   = 16 MB
  unsigned short* Ttb = (unsigned short*)(w8 + (40u<<20));     // 1024*512*2      = 1 MB
  unsigned short* Fb  = (unsigned short*)(w8 + (41u<<20));     // 8192*512*2      = 8 MB
  float* gpart        = (float*)(w8 + (49u<<20));              // 128*512*4       = 256 KB
  float* g            = (float*)(w8 + (49u<<20) + 262144);     // 512*4
  float* invr         = (float*)(w8 + (49u<<20) + 264192);     // 8192*4
  float* partials     = (float*)(w8 + (49u<<20) + 296960);     // 512*4

  hipLaunchKernelGGL(k_prep, dim3(1536), dim3(256), 0, stream, F, L, FbT, Fb, gpart, PbT);

  void* args[] = {(void*)&PbT, (void*)&FbT, (void*)&Tpb, (void*)&gpart, (void*)&g,
                  (void*)&Fb, (void*)&Ttb, (void*)&invr, (void*)&partials, (void*)&out};
  hipLaunchCooperativeKernel((const void*)k_main, dim3(512), dim3(256), args, 0, stream);
}

// Round 9
// 68.942 us; speedup vs baseline: 3.6592x; 3.6592x over previous
//
#include <hip/hip_runtime.h>
#include <math.h>

#define NN 8192
#define DD 512
#define CC 1000
#define CP 1024   // padded C
#define CPD (CP*DD)

typedef __attribute__((ext_vector_type(8))) short short8;     // bf16x8 MFMA frag
typedef __attribute__((ext_vector_type(4))) float f32x4;
typedef __attribute__((ext_vector_type(4))) unsigned short us4;
typedef __attribute__((ext_vector_type(8))) unsigned short us8;
typedef __attribute__((ext_vector_type(4))) unsigned int ui4;

__device__ __forceinline__ float bf2f(unsigned short u){
  union{unsigned int i; float f;} v; v.i = ((unsigned int)u)<<16; return v.f;
}
__device__ __forceinline__ unsigned short f2bf(float f){
  union{float f; unsigned int i;} v; v.f = f;
  unsigned int r = v.i + 0x7FFF + ((v.i>>16)&1);   // RNE
  return (unsigned short)(r>>16);
}
__device__ __forceinline__ float waveRedSum(float v){
  #pragma unroll
  for(int o=32;o;o>>=1) v += __shfl_xor(v,o,64);
  return v;
}
__device__ __forceinline__ float waveRedMax(float v){
  #pragma unroll
  for(int o=32;o;o>>=1) v = fmaxf(v,__shfl_xor(v,o,64));
  return v;
}
__device__ __forceinline__ void gload_lds16(const void* g, void* l){
  __builtin_amdgcn_global_load_lds((const __attribute__((address_space(1))) void*)g,
                                   (__attribute__((address_space(3))) void*)l, 16, 0, 0);
}

// ---- K1: merged prep. Blocks interleaved 2 castF : 1 softmaxT (512 groups of 3).
__global__ __launch_bounds__(256) void k_prep(const float* __restrict__ F,
                                              const float* __restrict__ L,
                                              unsigned short* __restrict__ FbT,
                                              unsigned short* __restrict__ Fb,
                                              float* __restrict__ gpart,
                                              unsigned short* __restrict__ PbT){
  __shared__ __align__(16) char smem[8*1028*4];   // 32.9 KB union
  int bid = blockIdx.x;
  int grp = bid/3, r = bid - grp*3;
  int t = threadIdx.x;

  if(r < 2){
    // ---------- castF path, block index cb in [0,1024) ----------
    int cb = grp*2 + r;
    unsigned short* lds = (unsigned short*)smem;           // [64*68]
    float* gq = (float*)(smem + 64*68*2);                  // [16*64]
    int i0 = (cb & 127)*64, d0 = (cb >> 7)*64;
    int cx = t&15, ry = t>>4;
    float ca0=0.f,ca1=0.f,ca2=0.f,ca3=0.f;
    #pragma unroll
    for(int rr=0;rr<4;rr++){
      int row = rr*16 + ry;
      f32x4 fv = *(const f32x4*)&F[(size_t)(i0+row)*DD + d0 + cx*4];
      us4 u; u[0]=f2bf(fv[0]); u[1]=f2bf(fv[1]); u[2]=f2bf(fv[2]); u[3]=f2bf(fv[3]);
      *(us4*)&lds[row*68 + cx*4] = u;
      *(us4*)&Fb[(size_t)(i0+row)*DD + d0 + cx*4] = u;
      ca0+=fv[0]; ca1+=fv[1]; ca2+=fv[2]; ca3+=fv[3];
    }
    {
      f32x4 cv; cv[0]=ca0; cv[1]=ca1; cv[2]=ca2; cv[3]=ca3;
      *(f32x4*)&gq[ry*64 + cx*4] = cv;
    }
    __syncthreads();
    #pragma unroll
    for(int rr=0;rr<4;rr++){
      int d = rr*16 + ry;
      us4 u;
      #pragma unroll
      for(int q=0;q<4;q++) u[q] = lds[(cx*4+q)*68 + d];
      *(us4*)&FbT[(size_t)(d0+d)*NN + i0 + cx*4] = u;
    }
    __syncthreads();
    if(t<64){
      float s=0.f;
      #pragma unroll
      for(int j=0;j<16;j++) s += gq[j*64+t];
      gpart[(cb&127)*DD + d0 + t] = s;
    }
  } else {
    // ---------- softmaxT path, block index sb in [0,512) ----------
    int sb = grp;
    unsigned int (*lt)[1028] = (unsigned int(*)[1028])smem;
    int l = t&63, w = t>>6;
    int i0 = sb*16;
    #pragma unroll
    for(int q=0;q<4;q++){
      int rr = w*4 + q;
      int row = i0 + rr;
      const float* lr = L + (size_t)row*CC;
      float v[16]; float mx = -1e30f;
      #pragma unroll
      for(int k=0;k<16;k++){ int c = l + 64*k; v[k] = (c<CC)? lr[c] : -1e30f; mx = fmaxf(mx,v[k]); }
      mx = waveRedMax(mx);
      float s = 0.f;
      #pragma unroll
      for(int k=0;k<16;k++){ v[k] = __expf(v[k]-mx); s += v[k]; }
      s = waveRedSum(s);
      float inv = 1.0f/s;
      #pragma unroll
      for(int k=0;k<16;k++){
        int c = l + 64*k;
        float p = v[k]*inv + 1e-8f;
        unsigned short h = (c<CC)? f2bf(p) : (unsigned short)0;
        *((unsigned short*)&lt[rr>>1][c] + (rr&1)) = h;
      }
    }
    __syncthreads();
    #pragma unroll
    for(int k=0;k<4;k++){
      int c = t + 256*k;
      ui4 a, b;
      #pragma unroll
      for(int j=0;j<4;j++){ a[j] = lt[j][c]; b[j] = lt[j+4][c]; }
      *(ui4*)&PbT[(size_t)c*NN + i0]     = a;
      *(ui4*)&PbT[(size_t)c*NN + i0 + 8] = b;
    }
  }
}

// ---- K2: GEMM1 (blocks 0..511, XCD-swizzled) + gred (blocks 512..519)
__global__ __launch_bounds__(256,2) void k_gemm1(const unsigned short* __restrict__ A,  // PbT [1024][8192]
                                                 const unsigned short* __restrict__ B,  // FbT [512][8192]
                                                 unsigned short* __restrict__ Tpb,
                                                 const float* __restrict__ gpart,
                                                 float* __restrict__ g){
  __shared__ unsigned short Al[128*64];
  __shared__ unsigned short Bl[128*64];
  __shared__ float rs[4][64];
  int bid = blockIdx.x;
  int t = threadIdx.x;
  if(bid >= 512){
    int gb = bid - 512;
    int d = gb*64 + (t&63);
    int q = t>>6;
    float s = 0.f;
    #pragma unroll
    for(int j=0;j<32;j++) s += gpart[(size_t)(q*32+j)*DD + d];
    rs[q][t&63] = s;
    __syncthreads();
    if(q==0) g[d] = rs[0][t&63]+rs[1][t&63]+rs[2][t&63]+rs[3][t&63];
    return;
  }
  // XCD-chunked bijective swizzle: XCD x gets L in [x*64, x*64+64) = 2 full k-chunks
  int Lsw = (bid&7)*64 + (bid>>3);
  int l = t&63, w = t>>6;
  int bx = Lsw & 7, by = (Lsw>>3) & 3, bz = Lsw>>5;
  int m0 = bx*128, n0 = by*128;
  int k0 = bz*512;
  int wm = w>>1, wn = w&1;
  f32x4 acc[4][4] = {};
  int srow = w*32 + (l>>3);
  int scl  = (l&7) ^ (srow&7);                 // pre-swizzled source chunk
  const unsigned short* Ab = A + (size_t)(m0 + srow)*NN + k0 + scl*8;
  const unsigned short* Bb = B + (size_t)(n0 + srow)*NN + k0 + scl*8;
  unsigned short* AlB = Al + (w*32)*64;
  unsigned short* BlB = Bl + (w*32)*64;

  for(int kt=0; kt<512; kt+=64){
    __syncthreads();
    #pragma unroll
    for(int q=0;q<4;q++){
      gload_lds16(Ab + (size_t)q*8*NN + kt, AlB + q*8*64);
      gload_lds16(Bb + (size_t)q*8*NN + kt, BlB + q*8*64);
    }
    asm volatile("s_waitcnt vmcnt(0)" ::: "memory");
    __syncthreads();
    #pragma unroll
    for(int ks=0;ks<2;ks++){
      short8 af[4], bf[4];
      #pragma unroll
      for(int mi=0;mi<4;mi++){
        int rr = wm*64 + mi*16 + (l&15);
        int ch = ((ks<<2) + (l>>4)) ^ (rr&7);
        af[mi] = *(const short8*)&Al[rr*64 + ch*8];
      }
      #pragma unroll
      for(int ni=0;ni<4;ni++){
        int rr = wn*64 + ni*16 + (l&15);
        int ch = ((ks<<2) + (l>>4)) ^ (rr&7);
        bf[ni] = *(const short8*)&Bl[rr*64 + ch*8];
      }
      #pragma unroll
      for(int mi=0;mi<4;mi++)
        #pragma unroll
        for(int ni=0;ni<4;ni++)
          acc[mi][ni] = __builtin_amdgcn_mfma_f32_16x16x32_bf16(af[mi], bf[ni], acc[mi][ni], 0,0,0);
    }
  }
  unsigned short* Tz = Tpb + (size_t)bz*CPD;
  int rbase = (l>>4)*4;
  #pragma unroll
  for(int mi=0;mi<4;mi++){
    int c = m0 + wm*64 + mi*16 + rbase;
    #pragma unroll
    for(int ni=0;ni<4;ni++){
      int d = n0 + wn*64 + ni*16 + (l&15);
      #pragma unroll
      for(int j=0;j<4;j++)
        Tz[(size_t)(c+j)*DD + d] = f2bf(acc[mi][ni][j]);
    }
  }
}

// ---- K3: reduce 16 bf16 partials -> Ttb bf16 (phase 1) AND invr (phase 2)
__global__ __launch_bounds__(256) void k_redT(const unsigned short* __restrict__ Tpb,
                                              const unsigned short* __restrict__ Fb,
                                              const float* __restrict__ g,
                                              unsigned short* __restrict__ Ttb,
                                              float* __restrict__ invr){
  int t = threadIdx.x;
  size_t i = ((size_t)blockIdx.x*256 + (size_t)t)*8;
  f32x4 s0 = {0.f,0.f,0.f,0.f}, s1 = {0.f,0.f,0.f,0.f};
  #pragma unroll
  for(int z=0;z<16;z++){
    us8 v = *(const us8*)&Tpb[(size_t)z*CPD + i];
    s0[0]+=bf2f(v[0]); s0[1]+=bf2f(v[1]); s0[2]+=bf2f(v[2]); s0[3]+=bf2f(v[3]);
    s1[0]+=bf2f(v[4]); s1[1]+=bf2f(v[5]); s1[2]+=bf2f(v[6]); s1[3]+=bf2f(v[7]);
  }
  us8 u;
  u[0]=f2bf(s0[0]); u[1]=f2bf(s0[1]); u[2]=f2bf(s0[2]); u[3]=f2bf(s0[3]);
  u[4]=f2bf(s1[0]); u[5]=f2bf(s1[1]); u[6]=f2bf(s1[2]); u[7]=f2bf(s1[3]);
  *(us8*)&Ttb[i] = u;
  // phase 2: invr for rows blockIdx.x*32 .. +31 (8 lanes per row)
  int row = blockIdx.x*32 + (t>>3);
  int seg = (t&7)*64;
  const unsigned short* fr = Fb + (size_t)row*DD + seg;
  const float* gr = g + seg;
  float s = 0.f;
  #pragma unroll
  for(int j=0;j<8;j++){
    us8 f8 = *(const us8*)&fr[j*8];
    f32x4 ga = *(const f32x4*)&gr[j*8];
    f32x4 gb = *(const f32x4*)&gr[j*8+4];
    s += bf2f(f8[0])*ga[0]+bf2f(f8[1])*ga[1]+bf2f(f8[2])*ga[2]+bf2f(f8[3])*ga[3]
       + bf2f(f8[4])*gb[0]+bf2f(f8[5])*gb[1]+bf2f(f8[6])*gb[2]+bf2f(f8[7])*gb[3];
  }
  s += __shfl_xor(s,1,64); s += __shfl_xor(s,2,64); s += __shfl_xor(s,4,64);
  if((t&7)==0) invr[row] = 1.0f/(s - 1.0f);
}

// ---- K4: GEMM2 (1D 512 blocks, XCD-swizzled): M = Fb x Ttb^T; fused KL epilogue
__global__ __launch_bounds__(256,2) void k_gemm2(const unsigned short* __restrict__ Fb,   // [8192][512]
                                                 const unsigned short* __restrict__ Bt,   // Ttb [1024][512]
                                                 const unsigned short* __restrict__ PbT,  // [1024][8192]
                                                 const float* __restrict__ invr,
                                                 float* __restrict__ partials){
  __shared__ unsigned short Al[128*64];
  __shared__ unsigned short Bl[128*64];
  __shared__ float red[4];
  int bid = blockIdx.x;
  // XCD-chunked bijective swizzle: XCD x gets L in [x*64, x*64+64) = 8 m-panels x 8 n-tiles
  int Lsw = (bid&7)*64 + (bid>>3);
  int t = threadIdx.x, l = t&63, w = t>>6;
  int m0 = (Lsw>>3)*128, n0 = (Lsw&7)*128;
  int wm = w>>1, wn = w&1;
  f32x4 acc[4][4] = {};
  int srow = w*32 + (l>>3);
  int scl  = (l&7) ^ (srow&7);
  const unsigned short* Ab = Fb + (size_t)(m0 + srow)*DD + scl*8;
  const unsigned short* Bb = Bt + (size_t)(n0 + srow)*DD + scl*8;
  unsigned short* AlB = Al + (w*32)*64;
  unsigned short* BlB = Bl + (w*32)*64;

  for(int kt=0; kt<512; kt+=64){
    __syncthreads();
    #pragma unroll
    for(int q=0;q<4;q++){
      gload_lds16(Ab + (size_t)q*8*DD + kt, AlB + q*8*64);
      gload_lds16(Bb + (size_t)q*8*DD + kt, BlB + q*8*64);
    }
    asm volatile("s_waitcnt vmcnt(0)" ::: "memory");
    __syncthreads();
    #pragma unroll
    for(int ks=0;ks<2;ks++){
      short8 af[4], bf[4];
      #pragma unroll
      for(int mi=0;mi<4;mi++){
        int rr = wm*64 + mi*16 + (l&15);
        int ch = ((ks<<2) + (l>>4)) ^ (rr&7);
        af[mi] = *(const short8*)&Al[rr*64 + ch*8];
      }
      #pragma unroll
      for(int ni=0;ni<4;ni++){
        int rr = wn*64 + ni*16 + (l&15);
        int ch = ((ks<<2) + (l>>4)) ^ (rr&7);
        bf[ni] = *(const short8*)&Bl[rr*64 + ch*8];
      }
      #pragma unroll
      for(int mi=0;mi<4;mi++)
        #pragma unroll
        for(int ni=0;ni<4;ni++)
          acc[mi][ni] = __builtin_amdgcn_mfma_f32_16x16x32_bf16(af[mi], bf[ni], acc[mi][ni], 0,0,0);
    }
  }
  // KL epilogue (fast log: ws*log(ws/p) = ws*(__logf(ws)-__logf(p)))
  float kl = 0.f;
  int rbase = (l>>4)*4;
  #pragma unroll
  for(int mi=0;mi<4;mi++){
    int i_base = m0 + wm*64 + mi*16 + rbase;
    f32x4 ir4 = *(const f32x4*)&invr[i_base];
    #pragma unroll
    for(int ni=0;ni<4;ni++){
      int c = n0 + wn*64 + ni*16 + (l&15);
      if(c < CC){
        us4 p4 = *(const us4*)&PbT[(size_t)c*NN + i_base];
        #pragma unroll
        for(int j=0;j<4;j++){
          float p = bf2f(p4[j]);
          float ws = (acc[mi][ni][j] - p) * ir4[j];
          kl += ws * (__logf(ws) - __logf(p));
        }
      }
    }
  }
  kl = waveRedSum(kl);
  if(l==0) red[w]=kl;
  __syncthreads();
  if(t==0) partials[Lsw] = red[0]+red[1]+red[2]+red[3];
}

// ---- K5: finalize
__global__ __launch_bounds__(64) void k_finalize(const float* __restrict__ partials,
                                                 float* __restrict__ out){
  int l = threadIdx.x;
  double s = 0.0;
  for(int j=l; j<512; j+=64) s += (double)partials[j];
  #pragma unroll
  for(int o=32;o;o>>=1) s += __shfl_xor(s,o,64);
  if(l==0) out[0] = (float)(s / (double)NN);
}

extern "C" void kernel_launch(void* const* d_in, const int* in_sizes, int n_in,
                              void* d_out, int out_size, void* d_ws, size_t ws_size,
                              hipStream_t stream){
  const float* F = (const float*)d_in[0];   // [8192][512]
  const float* L = (const float*)d_in[1];   // [8192][1000]
  float* out = (float*)d_out;

  unsigned char* w8 = (unsigned char*)d_ws;
  unsigned short* FbT = (unsigned short*)w8;                   // 512*8192*2      = 8 MB
  unsigned short* PbT = (unsigned short*)(w8 + (8u<<20));      // 1024*8192*2     = 16 MB
  unsigned short* Tpb = (unsigned short*)(w8 + (24u<<20));     // 16*1024*512*2   = 16 MB
  unsigned short* Ttb = (unsigned short*)(w8 + (40u<<20));     // 1024*512*2      = 1 MB
  unsigned short* Fb  = (unsigned short*)(w8 + (41u<<20));     // 8192*512*2      = 8 MB
  float* gpart        = (float*)(w8 + (49u<<20));              // 128*512*4       = 256 KB
  float* g            = (float*)(w8 + (49u<<20) + 262144);     // 512*4
  float* invr         = (float*)(w8 + (49u<<20) + 264192);     // 8192*4
  float* partials     = (float*)(w8 + (49u<<20) + 296960);     // 512*4

  hipLaunchKernelGGL(k_prep,     dim3(1536),   dim3(256), 0, stream, F, L, FbT, Fb, gpart, PbT);
  hipLaunchKernelGGL(k_gemm1,    dim3(520),    dim3(256), 0, stream, PbT, FbT, Tpb, gpart, g);
  hipLaunchKernelGGL(k_redT,     dim3(256),    dim3(256), 0, stream, Tpb, Fb, g, Ttb, invr);
  hipLaunchKernelGGL(k_gemm2,    dim3(512),    dim3(256), 0, stream, Fb, Ttb, PbT, invr, partials);
  hipLaunchKernelGGL(k_finalize, dim3(1),      dim3(64),  0, stream, partials, out);
}

// Round 10
// 67.939 us; speedup vs baseline: 3.7132x; 1.0148x over previous
//
#include <hip/hip_runtime.h>
#include <math.h>

#define NN 8192
#define DD 512
#define CC 1000
#define CP 1024   // padded C
#define CPD (CP*DD)

typedef __attribute__((ext_vector_type(8))) short short8;     // bf16x8 MFMA frag
typedef __attribute__((ext_vector_type(4))) float f32x4;
typedef __attribute__((ext_vector_type(4))) unsigned short us4;
typedef __attribute__((ext_vector_type(8))) unsigned short us8;
typedef __attribute__((ext_vector_type(4))) unsigned int ui4;

__device__ __forceinline__ float bf2f(unsigned short u){
  union{unsigned int i; float f;} v; v.i = ((unsigned int)u)<<16; return v.f;
}
__device__ __forceinline__ unsigned short f2bf(float f){
  union{float f; unsigned int i;} v; v.f = f;
  unsigned int r = v.i + 0x7FFF + ((v.i>>16)&1);   // RNE
  return (unsigned short)(r>>16);
}
__device__ __forceinline__ float waveRedSum(float v){
  #pragma unroll
  for(int o=32;o;o>>=1) v += __shfl_xor(v,o,64);
  return v;
}
__device__ __forceinline__ float waveRedMax(float v){
  #pragma unroll
  for(int o=32;o;o>>=1) v = fmaxf(v,__shfl_xor(v,o,64));
  return v;
}
__device__ __forceinline__ void gload_lds16(const void* g, void* l){
  __builtin_amdgcn_global_load_lds((const __attribute__((address_space(1))) void*)g,
                                   (__attribute__((address_space(3))) void*)l, 16, 0, 0);
}

// ---- K1: merged prep. Blocks interleaved 2 castF : 1 softmaxT (512 groups of 3).
__global__ __launch_bounds__(256) void k_prep(const float* __restrict__ F,
                                              const float* __restrict__ L,
                                              unsigned short* __restrict__ FbT,
                                              unsigned short* __restrict__ Fb,
                                              float* __restrict__ gpart,
                                              unsigned short* __restrict__ PbT){
  __shared__ __align__(16) char smem[8*1028*4];   // 32.9 KB union
  int bid = blockIdx.x;
  int grp = bid/3, r = bid - grp*3;
  int t = threadIdx.x;

  if(r < 2){
    // ---------- castF path, block index cb in [0,1024) ----------
    int cb = grp*2 + r;
    unsigned short* lds = (unsigned short*)smem;           // [64*68]
    float* gq = (float*)(smem + 64*68*2);                  // [16*64]
    int i0 = (cb & 127)*64, d0 = (cb >> 7)*64;
    int cx = t&15, ry = t>>4;
    float ca0=0.f,ca1=0.f,ca2=0.f,ca3=0.f;
    #pragma unroll
    for(int rr=0;rr<4;rr++){
      int row = rr*16 + ry;
      f32x4 fv = *(const f32x4*)&F[(size_t)(i0+row)*DD + d0 + cx*4];
      us4 u; u[0]=f2bf(fv[0]); u[1]=f2bf(fv[1]); u[2]=f2bf(fv[2]); u[3]=f2bf(fv[3]);
      *(us4*)&lds[row*68 + cx*4] = u;
      *(us4*)&Fb[(size_t)(i0+row)*DD + d0 + cx*4] = u;
      ca0+=fv[0]; ca1+=fv[1]; ca2+=fv[2]; ca3+=fv[3];
    }
    {
      f32x4 cv; cv[0]=ca0; cv[1]=ca1; cv[2]=ca2; cv[3]=ca3;
      *(f32x4*)&gq[ry*64 + cx*4] = cv;
    }
    __syncthreads();
    #pragma unroll
    for(int rr=0;rr<4;rr++){
      int d = rr*16 + ry;
      us4 u;
      #pragma unroll
      for(int q=0;q<4;q++) u[q] = lds[(cx*4+q)*68 + d];
      *(us4*)&FbT[(size_t)(d0+d)*NN + i0 + cx*4] = u;
    }
    __syncthreads();
    if(t<64){
      float s=0.f;
      #pragma unroll
      for(int j=0;j<16;j++) s += gq[j*64+t];
      gpart[(cb&127)*DD + d0 + t] = s;
    }
  } else {
    // ---------- softmaxT path, block index sb in [0,512) ----------
    int sb = grp;
    unsigned int (*lt)[1028] = (unsigned int(*)[1028])smem;
    int l = t&63, w = t>>6;
    int i0 = sb*16;
    #pragma unroll
    for(int q=0;q<4;q++){
      int rr = w*4 + q;
      int row = i0 + rr;
      const float* lr = L + (size_t)row*CC;
      float v[16]; float mx = -1e30f;
      #pragma unroll
      for(int k=0;k<16;k++){ int c = l + 64*k; v[k] = (c<CC)? lr[c] : -1e30f; mx = fmaxf(mx,v[k]); }
      mx = waveRedMax(mx);
      float s = 0.f;
      #pragma unroll
      for(int k=0;k<16;k++){ v[k] = __expf(v[k]-mx); s += v[k]; }
      s = waveRedSum(s);
      float inv = 1.0f/s;
      #pragma unroll
      for(int k=0;k<16;k++){
        int c = l + 64*k;
        float p = v[k]*inv + 1e-8f;
        unsigned short h = (c<CC)? f2bf(p) : (unsigned short)0;
        *((unsigned short*)&lt[rr>>1][c] + (rr&1)) = h;
      }
    }
    __syncthreads();
    #pragma unroll
    for(int k=0;k<4;k++){
      int c = t + 256*k;
      ui4 a, b;
      #pragma unroll
      for(int j=0;j<4;j++){ a[j] = lt[j][c]; b[j] = lt[j+4][c]; }
      *(ui4*)&PbT[(size_t)c*NN + i0]     = a;
      *(ui4*)&PbT[(size_t)c*NN + i0 + 8] = b;
    }
  }
}

// ---- K2: gred (blocks 0..7, first wave) + GEMM1 (blocks 8..519, XCD-swizzled)
__global__ __launch_bounds__(256,2) void k_gemm1(const unsigned short* __restrict__ A,  // PbT [1024][8192]
                                                 const unsigned short* __restrict__ B,  // FbT [512][8192]
                                                 unsigned short* __restrict__ Tpb,
                                                 const float* __restrict__ gpart,
                                                 float* __restrict__ g){
  __shared__ unsigned short Al[128*64];
  __shared__ unsigned short Bl[128*64];
  __shared__ float rs[4][64];
  int bid = blockIdx.x;
  int t = threadIdx.x;
  if(bid < 8){
    int d = bid*64 + (t&63);
    int q = t>>6;
    float s = 0.f;
    #pragma unroll
    for(int j=0;j<32;j++) s += gpart[(size_t)(q*32+j)*DD + d];
    rs[q][t&63] = s;
    __syncthreads();
    if(q==0) g[d] = rs[0][t&63]+rs[1][t&63]+rs[2][t&63]+rs[3][t&63];
    return;
  }
  int gb = bid - 8;
  // XCD-chunked bijective swizzle: XCD x gets L in [x*64, x*64+64) = 2 full k-chunks
  int Lsw = (gb&7)*64 + (gb>>3);
  int l = t&63, w = t>>6;
  int bx = Lsw & 7, by = (Lsw>>3) & 3, bz = Lsw>>5;
  int m0 = bx*128, n0 = by*128;
  int k0 = bz*512;
  int wm = w>>1, wn = w&1;
  f32x4 acc[4][4] = {};
  int srow = w*32 + (l>>3);
  int scl  = (l&7) ^ (srow&7);                 // pre-swizzled source chunk
  const unsigned short* Ab = A + (size_t)(m0 + srow)*NN + k0 + scl*8;
  const unsigned short* Bb = B + (size_t)(n0 + srow)*NN + k0 + scl*8;
  unsigned short* AlB = Al + (w*32)*64;
  unsigned short* BlB = Bl + (w*32)*64;

  for(int kt=0; kt<512; kt+=64){
    __syncthreads();
    #pragma unroll
    for(int q=0;q<4;q++){
      gload_lds16(Ab + (size_t)q*8*NN + kt, AlB + q*8*64);
      gload_lds16(Bb + (size_t)q*8*NN + kt, BlB + q*8*64);
    }
    asm volatile("s_waitcnt vmcnt(0)" ::: "memory");
    __syncthreads();
    #pragma unroll
    for(int ks=0;ks<2;ks++){
      short8 af[4], bf[4];
      #pragma unroll
      for(int mi=0;mi<4;mi++){
        int rr = wm*64 + mi*16 + (l&15);
        int ch = ((ks<<2) + (l>>4)) ^ (rr&7);
        af[mi] = *(const short8*)&Al[rr*64 + ch*8];
      }
      #pragma unroll
      for(int ni=0;ni<4;ni++){
        int rr = wn*64 + ni*16 + (l&15);
        int ch = ((ks<<2) + (l>>4)) ^ (rr&7);
        bf[ni] = *(const short8*)&Bl[rr*64 + ch*8];
      }
      #pragma unroll
      for(int mi=0;mi<4;mi++)
        #pragma unroll
        for(int ni=0;ni<4;ni++)
          acc[mi][ni] = __builtin_amdgcn_mfma_f32_16x16x32_bf16(af[mi], bf[ni], acc[mi][ni], 0,0,0);
    }
  }
  unsigned short* Tz = Tpb + (size_t)bz*CPD;
  int rbase = (l>>4)*4;
  #pragma unroll
  for(int mi=0;mi<4;mi++){
    int c = m0 + wm*64 + mi*16 + rbase;
    #pragma unroll
    for(int ni=0;ni<4;ni++){
      int d = n0 + wn*64 + ni*16 + (l&15);
      #pragma unroll
      for(int j=0;j<4;j++)
        Tz[(size_t)(c+j)*DD + d] = f2bf(acc[mi][ni][j]);
    }
  }
}

// ---- K3: reduce 16 bf16 partials -> Ttb bf16 (phase 1) AND invr (phase 2)
__global__ __launch_bounds__(256) void k_redT(const unsigned short* __restrict__ Tpb,
                                              const unsigned short* __restrict__ Fb,
                                              const float* __restrict__ g,
                                              unsigned short* __restrict__ Ttb,
                                              float* __restrict__ invr){
  int t = threadIdx.x;
  size_t i = ((size_t)blockIdx.x*256 + (size_t)t)*8;
  f32x4 s0 = {0.f,0.f,0.f,0.f}, s1 = {0.f,0.f,0.f,0.f};
  #pragma unroll
  for(int z=0;z<16;z++){
    us8 v = *(const us8*)&Tpb[(size_t)z*CPD + i];
    s0[0]+=bf2f(v[0]); s0[1]+=bf2f(v[1]); s0[2]+=bf2f(v[2]); s0[3]+=bf2f(v[3]);
    s1[0]+=bf2f(v[4]); s1[1]+=bf2f(v[5]); s1[2]+=bf2f(v[6]); s1[3]+=bf2f(v[7]);
  }
  us8 u;
  u[0]=f2bf(s0[0]); u[1]=f2bf(s0[1]); u[2]=f2bf(s0[2]); u[3]=f2bf(s0[3]);
  u[4]=f2bf(s1[0]); u[5]=f2bf(s1[1]); u[6]=f2bf(s1[2]); u[7]=f2bf(s1[3]);
  *(us8*)&Ttb[i] = u;
  // phase 2: invr for rows blockIdx.x*32 .. +31 (8 lanes per row)
  int row = blockIdx.x*32 + (t>>3);
  int seg = (t&7)*64;
  const unsigned short* fr = Fb + (size_t)row*DD + seg;
  const float* gr = g + seg;
  float s = 0.f;
  #pragma unroll
  for(int j=0;j<8;j++){
    us8 f8 = *(const us8*)&fr[j*8];
    f32x4 ga = *(const f32x4*)&gr[j*8];
    f32x4 gb = *(const f32x4*)&gr[j*8+4];
    s += bf2f(f8[0])*ga[0]+bf2f(f8[1])*ga[1]+bf2f(f8[2])*ga[2]+bf2f(f8[3])*ga[3]
       + bf2f(f8[4])*gb[0]+bf2f(f8[5])*gb[1]+bf2f(f8[6])*gb[2]+bf2f(f8[7])*gb[3];
  }
  s += __shfl_xor(s,1,64); s += __shfl_xor(s,2,64); s += __shfl_xor(s,4,64);
  if((t&7)==0) invr[row] = 1.0f/(s - 1.0f);
}

// ---- K4: GEMM2 (1D 512 blocks, XCD-swizzled): M = Fb x Ttb^T; fused KL epilogue
//      with LDS-staged P^T tile (coalesced 16 MB one-pass read)
__global__ __launch_bounds__(256,2) void k_gemm2(const unsigned short* __restrict__ Fb,   // [8192][512]
                                                 const unsigned short* __restrict__ Bt,   // Ttb [1024][512]
                                                 const unsigned short* __restrict__ PbT,  // [1024][8192]
                                                 const float* __restrict__ invr,
                                                 float* __restrict__ partials){
  // union LDS: phase A = Al[128*64] + Bl[128*64] (32 KB); phase B = Pl[128][136] (34 KB)
  __shared__ __align__(16) unsigned short smem[128*136];
  __shared__ float red[4];
  unsigned short* Al = smem;
  unsigned short* Bl = smem + 128*64;
  int bid = blockIdx.x;
  // XCD-chunked bijective swizzle: XCD x gets L in [x*64, x*64+64) = 8 m-panels x 8 n-tiles
  int Lsw = (bid&7)*64 + (bid>>3);
  int t = threadIdx.x, l = t&63, w = t>>6;
  int m0 = (Lsw>>3)*128, n0 = (Lsw&7)*128;
  int wm = w>>1, wn = w&1;
  f32x4 acc[4][4] = {};
  int srow = w*32 + (l>>3);
  int scl  = (l&7) ^ (srow&7);
  const unsigned short* Ab = Fb + (size_t)(m0 + srow)*DD + scl*8;
  const unsigned short* Bb = Bt + (size_t)(n0 + srow)*DD + scl*8;
  unsigned short* AlB = Al + (w*32)*64;
  unsigned short* BlB = Bl + (w*32)*64;

  for(int kt=0; kt<512; kt+=64){
    __syncthreads();
    #pragma unroll
    for(int q=0;q<4;q++){
      gload_lds16(Ab + (size_t)q*8*DD + kt, AlB + q*8*64);
      gload_lds16(Bb + (size_t)q*8*DD + kt, BlB + q*8*64);
    }
    asm volatile("s_waitcnt vmcnt(0)" ::: "memory");
    __syncthreads();
    #pragma unroll
    for(int ks=0;ks<2;ks++){
      short8 af[4], bf[4];
      #pragma unroll
      for(int mi=0;mi<4;mi++){
        int rr = wm*64 + mi*16 + (l&15);
        int ch = ((ks<<2) + (l>>4)) ^ (rr&7);
        af[mi] = *(const short8*)&Al[rr*64 + ch*8];
      }
      #pragma unroll
      for(int ni=0;ni<4;ni++){
        int rr = wn*64 + ni*16 + (l&15);
        int ch = ((ks<<2) + (l>>4)) ^ (rr&7);
        bf[ni] = *(const short8*)&Bl[rr*64 + ch*8];
      }
      #pragma unroll
      for(int mi=0;mi<4;mi++)
        #pragma unroll
        for(int ni=0;ni<4;ni++)
          acc[mi][ni] = __builtin_amdgcn_mfma_f32_16x16x32_bf16(af[mi], bf[ni], acc[mi][ni], 0,0,0);
    }
  }
  // stage P^T tile [c=n0..+127][i=m0..+127] into LDS, coalesced (row stride 136)
  __syncthreads();
  #pragma unroll
  for(int j=0;j<8;j++){
    int e = j*256 + t;
    int row = e >> 4;
    int ch  = e & 15;
    us8 v = *(const us8*)&PbT[(size_t)(n0+row)*NN + m0 + ch*8];
    *(us8*)&smem[row*136 + ch*8] = v;
  }
  __syncthreads();
  // KL epilogue from LDS (fast log: ws*log(ws/p) = ws*(__logf(ws)-__logf(p)))
  float kl = 0.f;
  int rbase = (l>>4)*4;
  #pragma unroll
  for(int mi=0;mi<4;mi++){
    int i_base = m0 + wm*64 + mi*16 + rbase;
    int ci = wm*64 + mi*16 + rbase;
    f32x4 ir4 = *(const f32x4*)&invr[i_base];
    #pragma unroll
    for(int ni=0;ni<4;ni++){
      int cr = wn*64 + ni*16 + (l&15);
      int c = n0 + cr;
      if(c < CC){
        us4 p4 = *(const us4*)&smem[cr*136 + ci];
        #pragma unroll
        for(int j=0;j<4;j++){
          float p = bf2f(p4[j]);
          float ws = (acc[mi][ni][j] - p) * ir4[j];
          kl += ws * (__logf(ws) - __logf(p));
        }
      }
    }
  }
  kl = waveRedSum(kl);
  if(l==0) red[w]=kl;
  __syncthreads();
  if(t==0) partials[Lsw] = red[0]+red[1]+red[2]+red[3];
}

// ---- K5: finalize
__global__ __launch_bounds__(64) void k_finalize(const float* __restrict__ partials,
                                                 float* __restrict__ out){
  int l = threadIdx.x;
  double s = 0.0;
  for(int j=l; j<512; j+=64) s += (double)partials[j];
  #pragma unroll
  for(int o=32;o;o>>=1) s += __shfl_xor(s,o,64);
  if(l==0) out[0] = (float)(s / (double)NN);
}

extern "C" void kernel_launch(void* const* d_in, const int* in_sizes, int n_in,
                              void* d_out, int out_size, void* d_ws, size_t ws_size,
                              hipStream_t stream){
  const float* F = (const float*)d_in[0];   // [8192][512]
  const float* L = (const float*)d_in[1];   // [8192][1000]
  float* out = (float*)d_out;

  unsigned char* w8 = (unsigned char*)d_ws;
  unsigned short* FbT = (unsigned short*)w8;                   // 512*8192*2      = 8 MB
  unsigned short* PbT = (unsigned short*)(w8 + (8u<<20));      // 1024*8192*2     = 16 MB
  unsigned short* Tpb = (unsigned short*)(w8 + (24u<<20));     // 16*1024*512*2   = 16 MB
  unsigned short* Ttb = (unsigned short*)(w8 + (40u<<20));     // 1024*512*2      = 1 MB
  unsigned short* Fb  = (unsigned short*)(w8 + (41u<<20));     // 8192*512*2      = 8 MB
  float* gpart        = (float*)(w8 + (49u<<20));              // 128*512*4       = 256 KB
  float* g            = (float*)(w8 + (49u<<20) + 262144);     // 512*4
  float* invr         = (float*)(w8 + (49u<<20) + 264192);     // 8192*4
  float* partials     = (float*)(w8 + (49u<<20) + 296960);     // 512*4

  hipLaunchKernelGGL(k_prep,     dim3(1536),   dim3(256), 0, stream, F, L, FbT, Fb, gpart, PbT);
  hipLaunchKernelGGL(k_gemm1,    dim3(520),    dim3(256), 0, stream, PbT, FbT, Tpb, gpart, g);
  hipLaunchKernelGGL(k_redT,     dim3(256),    dim3(256), 0, stream, Tpb, Fb, g, Ttb, invr);
  hipLaunchKernelGGL(k_gemm2,    dim3(512),    dim3(256), 0, stream, Fb, Ttb, PbT, invr, partials);
  hipLaunchKernelGGL(k_finalize, dim3(1),      dim3(64),  0, stream, partials, out);
}

// Round 11
// 66.554 us; speedup vs baseline: 3.7904x; 1.0208x over previous
//
#include <hip/hip_runtime.h>
#include <math.h>

#define NN 8192
#define DD 512
#define CC 1000
#define CP 1024   // padded C
#define CPD (CP*DD)

typedef __attribute__((ext_vector_type(8))) short short8;     // bf16x8 MFMA frag
typedef __attribute__((ext_vector_type(4))) float f32x4;
typedef __attribute__((ext_vector_type(4))) unsigned short us4;
typedef __attribute__((ext_vector_type(8))) unsigned short us8;
typedef __attribute__((ext_vector_type(4))) unsigned int ui4;

__device__ __forceinline__ float bf2f(unsigned short u){
  union{unsigned int i; float f;} v; v.i = ((unsigned int)u)<<16; return v.f;
}
__device__ __forceinline__ unsigned short f2bf(float f){
  union{float f; unsigned int i;} v; v.f = f;
  unsigned int r = v.i + 0x7FFF + ((v.i>>16)&1);   // RNE
  return (unsigned short)(r>>16);
}
__device__ __forceinline__ float waveRedSum(float v){
  #pragma unroll
  for(int o=32;o;o>>=1) v += __shfl_xor(v,o,64);
  return v;
}
__device__ __forceinline__ float waveRedMax(float v){
  #pragma unroll
  for(int o=32;o;o>>=1) v = fmaxf(v,__shfl_xor(v,o,64));
  return v;
}
__device__ __forceinline__ void gload_lds16(const void* g, void* l){
  __builtin_amdgcn_global_load_lds((const __attribute__((address_space(1))) void*)g,
                                   (__attribute__((address_space(3))) void*)l, 16, 0, 0);
}

// ---- K1: merged prep. Blocks interleaved 2 castF : 1 softmaxT (512 groups of 3).
__global__ __launch_bounds__(256) void k_prep(const float* __restrict__ F,
                                              const float* __restrict__ L,
                                              unsigned short* __restrict__ FbT,
                                              unsigned short* __restrict__ Fb,
                                              float* __restrict__ gpart,
                                              unsigned short* __restrict__ PbT){
  __shared__ __align__(16) char smem[8*1028*4];   // 32.9 KB union
  int bid = blockIdx.x;
  int grp = bid/3, r = bid - grp*3;
  int t = threadIdx.x;

  if(r < 2){
    // ---------- castF path, block index cb in [0,1024) ----------
    int cb = grp*2 + r;
    unsigned short* lds = (unsigned short*)smem;           // [64*68]
    float* gq = (float*)(smem + 64*68*2);                  // [16*64]
    int i0 = (cb & 127)*64, d0 = (cb >> 7)*64;
    int cx = t&15, ry = t>>4;
    float ca0=0.f,ca1=0.f,ca2=0.f,ca3=0.f;
    #pragma unroll
    for(int rr=0;rr<4;rr++){
      int row = rr*16 + ry;
      f32x4 fv = *(const f32x4*)&F[(size_t)(i0+row)*DD + d0 + cx*4];
      us4 u; u[0]=f2bf(fv[0]); u[1]=f2bf(fv[1]); u[2]=f2bf(fv[2]); u[3]=f2bf(fv[3]);
      *(us4*)&lds[row*68 + cx*4] = u;
      *(us4*)&Fb[(size_t)(i0+row)*DD + d0 + cx*4] = u;
      ca0+=fv[0]; ca1+=fv[1]; ca2+=fv[2]; ca3+=fv[3];
    }
    {
      f32x4 cv; cv[0]=ca0; cv[1]=ca1; cv[2]=ca2; cv[3]=ca3;
      *(f32x4*)&gq[ry*64 + cx*4] = cv;
    }
    __syncthreads();
    #pragma unroll
    for(int rr=0;rr<4;rr++){
      int d = rr*16 + ry;
      us4 u;
      #pragma unroll
      for(int q=0;q<4;q++) u[q] = lds[(cx*4+q)*68 + d];
      *(us4*)&FbT[(size_t)(d0+d)*NN + i0 + cx*4] = u;
    }
    __syncthreads();
    if(t<64){
      float s=0.f;
      #pragma unroll
      for(int j=0;j<16;j++) s += gq[j*64+t];
      gpart[(cb&127)*DD + d0 + t] = s;
    }
  } else {
    // ---------- softmaxT path, block index sb in [0,512) ----------
    int sb = grp;
    unsigned int (*lt)[1028] = (unsigned int(*)[1028])smem;
    int l = t&63, w = t>>6;
    int i0 = sb*16;
    #pragma unroll
    for(int q=0;q<4;q++){
      int rr = w*4 + q;
      int row = i0 + rr;
      const float* lr = L + (size_t)row*CC;
      float v[16]; float mx = -1e30f;
      #pragma unroll
      for(int k=0;k<16;k++){ int c = l + 64*k; v[k] = (c<CC)? lr[c] : -1e30f; mx = fmaxf(mx,v[k]); }
      mx = waveRedMax(mx);
      float s = 0.f;
      #pragma unroll
      for(int k=0;k<16;k++){ v[k] = __expf(v[k]-mx); s += v[k]; }
      s = waveRedSum(s);
      float inv = 1.0f/s;
      #pragma unroll
      for(int k=0;k<16;k++){
        int c = l + 64*k;
        float p = v[k]*inv + 1e-8f;
        unsigned short h = (c<CC)? f2bf(p) : (unsigned short)0;
        *((unsigned short*)&lt[rr>>1][c] + (rr&1)) = h;
      }
    }
    __syncthreads();
    #pragma unroll
    for(int k=0;k<4;k++){
      int c = t + 256*k;
      ui4 a, b;
      #pragma unroll
      for(int j=0;j<4;j++){ a[j] = lt[j][c]; b[j] = lt[j+4][c]; }
      *(ui4*)&PbT[(size_t)c*NN + i0]     = a;
      *(ui4*)&PbT[(size_t)c*NN + i0 + 8] = b;
    }
  }
}

// ---- K2: gred (blocks 0..7) + GEMM1 (blocks 8..519, XCD-swizzled, 2-phase dbuf)
__global__ __launch_bounds__(256,2) void k_gemm1(const unsigned short* __restrict__ A,  // PbT [1024][8192]
                                                 const unsigned short* __restrict__ B,  // FbT [512][8192]
                                                 unsigned short* __restrict__ Tpb,
                                                 const float* __restrict__ gpart,
                                                 float* __restrict__ g){
  __shared__ __align__(16) unsigned short smem[4*8192];   // A0 B0 A1 B1, 64 KB
  __shared__ float rs[4][64];
  int bid = blockIdx.x;
  int t = threadIdx.x;
  if(bid < 8){
    int d = bid*64 + (t&63);
    int q = t>>6;
    float s = 0.f;
    #pragma unroll
    for(int j=0;j<32;j++) s += gpart[(size_t)(q*32+j)*DD + d];
    rs[q][t&63] = s;
    __syncthreads();
    if(q==0) g[d] = rs[0][t&63]+rs[1][t&63]+rs[2][t&63]+rs[3][t&63];
    return;
  }
  int gb = bid - 8;
  int Lsw = (gb&7)*64 + (gb>>3);     // XCD-chunked bijective swizzle
  int l = t&63, w = t>>6;
  int bx = Lsw & 7, by = (Lsw>>3) & 3, bz = Lsw>>5;
  int m0 = bx*128, n0 = by*128;
  int k0 = bz*512;
  int wm = w>>1, wn = w&1;
  f32x4 acc[4][4] = {};
  int srow = w*32 + (l>>3);
  int scl  = (l&7) ^ (srow&7);                 // pre-swizzled source chunk
  const unsigned short* Ab = A + (size_t)(m0 + srow)*NN + k0 + scl*8;
  const unsigned short* Bb = B + (size_t)(n0 + srow)*NN + k0 + scl*8;
  int ldsOff = (w*32)*64;

  // prologue: stage tile 0 into buffer 0
  #pragma unroll
  for(int q=0;q<4;q++){
    gload_lds16(Ab + (size_t)q*8*NN, smem + ldsOff + q*8*64);
    gload_lds16(Bb + (size_t)q*8*NN, smem + 8192 + ldsOff + q*8*64);
  }
  int cur = 0;
  for(int kt=0; kt<512; kt+=64){
    if(kt+64 < 512){
      unsigned short* An = smem + (cur^1)*16384 + ldsOff;
      unsigned short* Bn = smem + (cur^1)*16384 + 8192 + ldsOff;
      #pragma unroll
      for(int q=0;q<4;q++){
        gload_lds16(Ab + (size_t)q*8*NN + kt + 64, An + q*8*64);
        gload_lds16(Bb + (size_t)q*8*NN + kt + 64, Bn + q*8*64);
      }
      asm volatile("s_waitcnt vmcnt(8)" ::: "memory");   // drain ONLY current tile
    } else {
      asm volatile("s_waitcnt vmcnt(0)" ::: "memory");
    }
    __builtin_amdgcn_s_barrier();                        // raw: no compiler vmcnt(0) drain
    const unsigned short* Ac = smem + cur*16384;
    const unsigned short* Bc = smem + cur*16384 + 8192;
    #pragma unroll
    for(int ks=0;ks<2;ks++){
      short8 af[4], bf[4];
      #pragma unroll
      for(int mi=0;mi<4;mi++){
        int rr = wm*64 + mi*16 + (l&15);
        int ch = ((ks<<2) + (l>>4)) ^ (rr&7);
        af[mi] = *(const short8*)&Ac[rr*64 + ch*8];
      }
      #pragma unroll
      for(int ni=0;ni<4;ni++){
        int rr = wn*64 + ni*16 + (l&15);
        int ch = ((ks<<2) + (l>>4)) ^ (rr&7);
        bf[ni] = *(const short8*)&Bc[rr*64 + ch*8];
      }
      #pragma unroll
      for(int mi=0;mi<4;mi++)
        #pragma unroll
        for(int ni=0;ni<4;ni++)
          acc[mi][ni] = __builtin_amdgcn_mfma_f32_16x16x32_bf16(af[mi], bf[ni], acc[mi][ni], 0,0,0);
    }
    __builtin_amdgcn_s_barrier();                        // reads done before next overwrite
    cur ^= 1;
  }
  unsigned short* Tz = Tpb + (size_t)bz*CPD;
  int rbase = (l>>4)*4;
  #pragma unroll
  for(int mi=0;mi<4;mi++){
    int c = m0 + wm*64 + mi*16 + rbase;
    #pragma unroll
    for(int ni=0;ni<4;ni++){
      int d = n0 + wn*64 + ni*16 + (l&15);
      #pragma unroll
      for(int j=0;j<4;j++)
        Tz[(size_t)(c+j)*DD + d] = f2bf(acc[mi][ni][j]);
    }
  }
}

// ---- K3: reduce 16 bf16 partials -> Ttb bf16 (phase 1) AND invr (phase 2)
__global__ __launch_bounds__(256) void k_redT(const unsigned short* __restrict__ Tpb,
                                              const unsigned short* __restrict__ Fb,
                                              const float* __restrict__ g,
                                              unsigned short* __restrict__ Ttb,
                                              float* __restrict__ invr){
  int t = threadIdx.x;
  size_t i = ((size_t)blockIdx.x*256 + (size_t)t)*8;
  f32x4 s0 = {0.f,0.f,0.f,0.f}, s1 = {0.f,0.f,0.f,0.f};
  #pragma unroll
  for(int z=0;z<16;z++){
    us8 v = *(const us8*)&Tpb[(size_t)z*CPD + i];
    s0[0]+=bf2f(v[0]); s0[1]+=bf2f(v[1]); s0[2]+=bf2f(v[2]); s0[3]+=bf2f(v[3]);
    s1[0]+=bf2f(v[4]); s1[1]+=bf2f(v[5]); s1[2]+=bf2f(v[6]); s1[3]+=bf2f(v[7]);
  }
  us8 u;
  u[0]=f2bf(s0[0]); u[1]=f2bf(s0[1]); u[2]=f2bf(s0[2]); u[3]=f2bf(s0[3]);
  u[4]=f2bf(s1[0]); u[5]=f2bf(s1[1]); u[6]=f2bf(s1[2]); u[7]=f2bf(s1[3]);
  *(us8*)&Ttb[i] = u;
  // phase 2: invr for rows blockIdx.x*32 .. +31 (8 lanes per row)
  int row = blockIdx.x*32 + (t>>3);
  int seg = (t&7)*64;
  const unsigned short* fr = Fb + (size_t)row*DD + seg;
  const float* gr = g + seg;
  float s = 0.f;
  #pragma unroll
  for(int j=0;j<8;j++){
    us8 f8 = *(const us8*)&fr[j*8];
    f32x4 ga = *(const f32x4*)&gr[j*8];
    f32x4 gb = *(const f32x4*)&gr[j*8+4];
    s += bf2f(f8[0])*ga[0]+bf2f(f8[1])*ga[1]+bf2f(f8[2])*ga[2]+bf2f(f8[3])*ga[3]
       + bf2f(f8[4])*gb[0]+bf2f(f8[5])*gb[1]+bf2f(f8[6])*gb[2]+bf2f(f8[7])*gb[3];
  }
  s += __shfl_xor(s,1,64); s += __shfl_xor(s,2,64); s += __shfl_xor(s,4,64);
  if((t&7)==0) invr[row] = 1.0f/(s - 1.0f);
}

// ---- K4: GEMM2 (1D 512 blocks, XCD-swizzled, 2-phase dbuf): M = Fb x Ttb^T; KL epilogue
__global__ __launch_bounds__(256,2) void k_gemm2(const unsigned short* __restrict__ Fb,   // [8192][512]
                                                 const unsigned short* __restrict__ Bt,   // Ttb [1024][512]
                                                 const unsigned short* __restrict__ PbT,  // [1024][8192]
                                                 const float* __restrict__ invr,
                                                 float* __restrict__ partials){
  __shared__ __align__(16) unsigned short smem[4*8192];   // A0 B0 A1 B1; epilogue P[128][136]
  __shared__ float red[4];
  int bid = blockIdx.x;
  int Lsw = (bid&7)*64 + (bid>>3);   // XCD-chunked bijective swizzle
  int t = threadIdx.x, l = t&63, w = t>>6;
  int m0 = (Lsw>>3)*128, n0 = (Lsw&7)*128;
  int wm = w>>1, wn = w&1;
  f32x4 acc[4][4] = {};
  int srow = w*32 + (l>>3);
  int scl  = (l&7) ^ (srow&7);
  const unsigned short* Ab = Fb + (size_t)(m0 + srow)*DD + scl*8;
  const unsigned short* Bb = Bt + (size_t)(n0 + srow)*DD + scl*8;
  int ldsOff = (w*32)*64;

  // prologue: stage tile 0 into buffer 0
  #pragma unroll
  for(int q=0;q<4;q++){
    gload_lds16(Ab + (size_t)q*8*DD, smem + ldsOff + q*8*64);
    gload_lds16(Bb + (size_t)q*8*DD, smem + 8192 + ldsOff + q*8*64);
  }
  int cur = 0;
  for(int kt=0; kt<512; kt+=64){
    if(kt+64 < 512){
      unsigned short* An = smem + (cur^1)*16384 + ldsOff;
      unsigned short* Bn = smem + (cur^1)*16384 + 8192 + ldsOff;
      #pragma unroll
      for(int q=0;q<4;q++){
        gload_lds16(Ab + (size_t)q*8*DD + kt + 64, An + q*8*64);
        gload_lds16(Bb + (size_t)q*8*DD + kt + 64, Bn + q*8*64);
      }
      asm volatile("s_waitcnt vmcnt(8)" ::: "memory");
    } else {
      asm volatile("s_waitcnt vmcnt(0)" ::: "memory");
    }
    __builtin_amdgcn_s_barrier();
    const unsigned short* Ac = smem + cur*16384;
    const unsigned short* Bc = smem + cur*16384 + 8192;
    #pragma unroll
    for(int ks=0;ks<2;ks++){
      short8 af[4], bf[4];
      #pragma unroll
      for(int mi=0;mi<4;mi++){
        int rr = wm*64 + mi*16 + (l&15);
        int ch = ((ks<<2) + (l>>4)) ^ (rr&7);
        af[mi] = *(const short8*)&Ac[rr*64 + ch*8];
      }
      #pragma unroll
      for(int ni=0;ni<4;ni++){
        int rr = wn*64 + ni*16 + (l&15);
        int ch = ((ks<<2) + (l>>4)) ^ (rr&7);
        bf[ni] = *(const short8*)&Bc[rr*64 + ch*8];
      }
      #pragma unroll
      for(int mi=0;mi<4;mi++)
        #pragma unroll
        for(int ni=0;ni<4;ni++)
          acc[mi][ni] = __builtin_amdgcn_mfma_f32_16x16x32_bf16(af[mi], bf[ni], acc[mi][ni], 0,0,0);
    }
    __builtin_amdgcn_s_barrier();
    cur ^= 1;
  }
  // stage P^T tile [c=n0..+127][i=m0..+127] into LDS, coalesced (row stride 136)
  __syncthreads();
  #pragma unroll
  for(int j=0;j<8;j++){
    int e = j*256 + t;
    int row = e >> 4;
    int ch  = e & 15;
    us8 v = *(const us8*)&PbT[(size_t)(n0+row)*NN + m0 + ch*8];
    *(us8*)&smem[row*136 + ch*8] = v;
  }
  __syncthreads();
  // KL epilogue from LDS (fast log: ws*log(ws/p) = ws*(__logf(ws)-__logf(p)))
  float kl = 0.f;
  int rbase = (l>>4)*4;
  #pragma unroll
  for(int mi=0;mi<4;mi++){
    int i_base = m0 + wm*64 + mi*16 + rbase;
    int ci = wm*64 + mi*16 + rbase;
    f32x4 ir4 = *(const f32x4*)&invr[i_base];
    #pragma unroll
    for(int ni=0;ni<4;ni++){
      int cr = wn*64 + ni*16 + (l&15);
      int c = n0 + cr;
      if(c < CC){
        us4 p4 = *(const us4*)&smem[cr*136 + ci];
        #pragma unroll
        for(int j=0;j<4;j++){
          float p = bf2f(p4[j]);
          float ws = (acc[mi][ni][j] - p) * ir4[j];
          kl += ws * (__logf(ws) - __logf(p));
        }
      }
    }
  }
  kl = waveRedSum(kl);
  if(l==0) red[w]=kl;
  __syncthreads();
  if(t==0) partials[Lsw] = red[0]+red[1]+red[2]+red[3];
}

// ---- K5: finalize
__global__ __launch_bounds__(64) void k_finalize(const float* __restrict__ partials,
                                                 float* __restrict__ out){
  int l = threadIdx.x;
  double s = 0.0;
  for(int j=l; j<512; j+=64) s += (double)partials[j];
  #pragma unroll
  for(int o=32;o;o>>=1) s += __shfl_xor(s,o,64);
  if(l==0) out[0] = (float)(s / (double)NN);
}

extern "C" void kernel_launch(void* const* d_in, const int* in_sizes, int n_in,
                              void* d_out, int out_size, void* d_ws, size_t ws_size,
                              hipStream_t stream){
  const float* F = (const float*)d_in[0];   // [8192][512]
  const float* L = (const float*)d_in[1];   // [8192][1000]
  float* out = (float*)d_out;

  unsigned char* w8 = (unsigned char*)d_ws;
  unsigned short* FbT = (unsigned short*)w8;                   // 512*8192*2      = 8 MB
  unsigned short* PbT = (unsigned short*)(w8 + (8u<<20));      // 1024*8192*2     = 16 MB
  unsigned short* Tpb = (unsigned short*)(w8 + (24u<<20));     // 16*1024*512*2   = 16 MB
  unsigned short* Ttb = (unsigned short*)(w8 + (40u<<20));     // 1024*512*2      = 1 MB
  unsigned short* Fb  = (unsigned short*)(w8 + (41u<<20));     // 8192*512*2      = 8 MB
  float* gpart        = (float*)(w8 + (49u<<20));              // 128*512*4       = 256 KB
  float* g            = (float*)(w8 + (49u<<20) + 262144);     // 512*4
  float* invr         = (float*)(w8 + (49u<<20) + 264192);     // 8192*4
  float* partials     = (float*)(w8 + (49u<<20) + 296960);     // 512*4

  hipLaunchKernelGGL(k_prep,     dim3(1536),   dim3(256), 0, stream, F, L, FbT, Fb, gpart, PbT);
  hipLaunchKernelGGL(k_gemm1,    dim3(520),    dim3(256), 0, stream, PbT, FbT, Tpb, gpart, g);
  hipLaunchKernelGGL(k_redT,     dim3(256),    dim3(256), 0, stream, Tpb, Fb, g, Ttb, invr);
  hipLaunchKernelGGL(k_gemm2,    dim3(512),    dim3(256), 0, stream, Fb, Ttb, PbT, invr, partials);
  hipLaunchKernelGGL(k_finalize, dim3(1),      dim3(64),  0, stream, partials, out);
}